// Round 1
// baseline (127.342 us; speedup 1.0000x reference)
//
#include <hip/hip_runtime.h>

typedef float v2f __attribute__((ext_vector_type(2)));

#define BLOCK 256
#define REG_N 8      // predict-points per thread (in registers)
#define CHUNK 512    // target-points staged in LDS per block (6 KB SoA)

// dmin[0..N)  = dist1 (min over targets for each predict point), uint-encoded float
// dmin[N..2N) = dist2 (min over predicts for each target point)
// Non-negative IEEE floats compare identically as unsigned ints -> atomicMin(uint).

__global__ void init_min(unsigned* __restrict__ dmin, int n2) {
    int i = blockIdx.x * blockDim.x + threadIdx.x;
    if (i < n2) dmin[i] = 0x7F800000u;  // +inf
}

__global__ __launch_bounds__(BLOCK) void chamfer_min(
    const float* __restrict__ predict, const float* __restrict__ target,
    unsigned* __restrict__ dmin, int N)
{
    const int dir = blockIdx.z;                    // 0: min over targets, 1: min over predicts
    const float* __restrict__ A = dir ? target : predict;   // points we own
    const float* __restrict__ B = dir ? predict : target;   // points we search
    unsigned* __restrict__ dm = dmin + dir * N;

    __shared__ float sx[CHUNK], sy[CHUNK], sz[CHUNK];

    const int tid = threadIdx.x;
    const int m0  = blockIdx.y * CHUNK;

    // Stage B chunk into LDS (SoA). Coalesced global reads, scattered LDS writes
    // (only 6 floats/thread — negligible vs inner loop).
    for (int f = tid; f < 3 * CHUNK; f += BLOCK) {
        float v = B[3 * m0 + f];
        int j = f / 3, c = f - 3 * j;
        if (c == 0) sx[j] = v; else if (c == 1) sy[j] = v; else sz[j] = v;
    }

    // This thread's REG_N owned points.
    float px[REG_N], py[REG_N], pz[REG_N];
    const int nbase = blockIdx.x * (BLOCK * REG_N) + tid;
    #pragma unroll
    for (int k = 0; k < REG_N; ++k) {
        int n = nbase + k * BLOCK;
        px[k] = A[3 * n + 0];
        py[k] = A[3 * n + 1];
        pz[k] = A[3 * n + 2];
    }

    __syncthreads();

    v2f best[REG_N];
    #pragma unroll
    for (int k = 0; k < REG_N; ++k) best[k] = (v2f){3.0e38f, 3.0e38f};

    const float4* __restrict__ sx4 = (const float4*)sx;
    const float4* __restrict__ sy4 = (const float4*)sy;
    const float4* __restrict__ sz4 = (const float4*)sz;

    // Inner loop: 4 target points per iteration (2x packed-f32 halves),
    // shared across REG_N owned points. VALU-bound by design.
    for (int m = 0; m < CHUNK / 4; ++m) {
        float4 X = sx4[m], Y = sy4[m], Z = sz4[m];
        v2f xa = {X.x, X.y}, xb = {X.z, X.w};
        v2f ya = {Y.x, Y.y}, yb = {Y.z, Y.w};
        v2f za = {Z.x, Z.y}, zb = {Z.z, Z.w};
        #pragma unroll
        for (int k = 0; k < REG_N; ++k) {
            v2f dxa = xa - px[k];
            v2f dya = ya - py[k];
            v2f dza = za - pz[k];
            v2f da  = dxa * dxa + dya * dya + dza * dza;
            v2f dxb = xb - px[k];
            v2f dyb = yb - py[k];
            v2f dzb = zb - pz[k];
            v2f db  = dxb * dxb + dyb * dyb + dzb * dzb;
            best[k].x = fminf(best[k].x, da.x);
            best[k].y = fminf(best[k].y, da.y);
            best[k].x = fminf(best[k].x, db.x);
            best[k].y = fminf(best[k].y, db.y);
        }
    }

    #pragma unroll
    for (int k = 0; k < REG_N; ++k) {
        float b = fminf(best[k].x, best[k].y);
        atomicMin(&dm[nbase + k * BLOCK], __float_as_uint(b));
    }
}

__global__ void chamfer_reduce(const unsigned* __restrict__ dmin, float* __restrict__ out, int N) {
    __shared__ double sacc[16];
    const int tid = threadIdx.x;
    double acc = 0.0;
    for (int i = tid; i < 2 * N; i += blockDim.x)
        acc += (double)__uint_as_float(dmin[i]);
    // wave64 reduction
    for (int off = 32; off; off >>= 1)
        acc += __shfl_down(acc, off, 64);
    const int wave = tid >> 6, lane = tid & 63;
    if (lane == 0) sacc[wave] = acc;
    __syncthreads();
    if (tid == 0) {
        double t = 0.0;
        int nw = blockDim.x >> 6;
        for (int w = 0; w < nw; ++w) t += sacc[w];
        out[0] = (float)(t / (double)N);   // mean(dist1) + mean(dist2), N == M
    }
}

extern "C" void kernel_launch(void* const* d_in, const int* in_sizes, int n_in,
                              void* d_out, int out_size, void* d_ws, size_t ws_size,
                              hipStream_t stream) {
    const float* predict = (const float*)d_in[0];
    const float* target  = (const float*)d_in[1];
    const int N = in_sizes[0] / 3;   // 16384 (shape [1,N,3])
    unsigned* dmin = (unsigned*)d_ws;

    init_min<<<dim3((2 * N + 255) / 256), dim3(256), 0, stream>>>(dmin, 2 * N);

    dim3 grid(N / (BLOCK * REG_N), N / CHUNK, 2);   // 8 x 32 x 2 = 512 blocks
    chamfer_min<<<grid, dim3(BLOCK), 0, stream>>>(predict, target, dmin, N);

    chamfer_reduce<<<1, dim3(1024), 0, stream>>>(dmin, (float*)d_out, N);
}

// Round 2
// 102.931 us; speedup vs baseline: 1.2372x; 1.2372x over previous
//
#include <hip/hip_runtime.h>

#define BLOCK 256
#define REG_N 4      // owned points per thread (registers)
#define CHUNK 512    // target points staged in LDS per block (8 KB SoA incl t^2)

// dmin[0..N)  = dist1 (min over targets for each predict point), uint-encoded float
// dmin[N..2N) = dist2 (min over predicts for each target point)
// Non-negative IEEE floats compare identically as unsigned ints -> atomicMin(uint).

__global__ void init_min(unsigned* __restrict__ dmin, int n2) {
    int i = blockIdx.x * blockDim.x + threadIdx.x;
    if (i < n2) dmin[i] = 0x7F800000u;  // +inf
}

__global__ __launch_bounds__(BLOCK) void chamfer_min(
    const float* __restrict__ predict, const float* __restrict__ target,
    unsigned* __restrict__ dmin, int N)
{
    const int dir = blockIdx.z;                    // 0: min over targets, 1: min over predicts
    const float* __restrict__ A = dir ? target : predict;   // points we own
    const float* __restrict__ B = dir ? predict : target;   // points we search
    unsigned* __restrict__ dm = dmin + dir * N;

    __shared__ float sx[CHUNK], sy[CHUNK], sz[CHUNK], st2[CHUNK];

    const int tid = threadIdx.x;
    const int m0  = blockIdx.y * CHUNK;

    // Stage B chunk into LDS (SoA) + per-target |t|^2.
    // 2 iterations per thread; tiny vs inner loop.
    for (int j = tid; j < CHUNK; j += BLOCK) {
        float x = B[3 * (m0 + j) + 0];
        float y = B[3 * (m0 + j) + 1];
        float z = B[3 * (m0 + j) + 2];
        sx[j] = x; sy[j] = y; sz[j] = z;
        st2[j] = __builtin_fmaf(x, x, __builtin_fmaf(y, y, z * z));
    }

    // This thread's REG_N owned points: precompute -2*p and |p|^2.
    float m2x[REG_N], m2y[REG_N], m2z[REG_N], p2[REG_N];
    const int nbase = blockIdx.x * (BLOCK * REG_N) + tid;
    #pragma unroll
    for (int k = 0; k < REG_N; ++k) {
        int n = nbase + k * BLOCK;
        float x = A[3 * n + 0], y = A[3 * n + 1], z = A[3 * n + 2];
        m2x[k] = -2.0f * x; m2y[k] = -2.0f * y; m2z[k] = -2.0f * z;
        p2[k]  = __builtin_fmaf(x, x, __builtin_fmaf(y, y, z * z));
    }

    __syncthreads();

    float best[REG_N];
    #pragma unroll
    for (int k = 0; k < REG_N; ++k) best[k] = 3.0e38f;

    const float4* __restrict__ sx4 = (const float4*)sx;
    const float4* __restrict__ sy4 = (const float4*)sy;
    const float4* __restrict__ sz4 = (const float4*)sz;
    const float4* __restrict__ st4 = (const float4*)st2;

    // Inner loop: 4 targets per iteration, shared across REG_N owned points.
    // Per pair: 3 v_fma_f32 + amortized 1 v_min_f32 (tree min) = 4 VALU instr.
    #pragma unroll 2
    for (int m = 0; m < CHUNK / 4; ++m) {
        float4 X = sx4[m], Y = sy4[m], Z = sz4[m], T = st4[m];
        #pragma unroll
        for (int k = 0; k < REG_N; ++k) {
            float d0 = __builtin_fmaf(m2x[k], X.x, T.x);
            float d1 = __builtin_fmaf(m2x[k], X.y, T.y);
            float d2 = __builtin_fmaf(m2x[k], X.z, T.z);
            float d3 = __builtin_fmaf(m2x[k], X.w, T.w);
            d0 = __builtin_fmaf(m2y[k], Y.x, d0);
            d1 = __builtin_fmaf(m2y[k], Y.y, d1);
            d2 = __builtin_fmaf(m2y[k], Y.z, d2);
            d3 = __builtin_fmaf(m2y[k], Y.w, d3);
            d0 = __builtin_fmaf(m2z[k], Z.x, d0);
            d1 = __builtin_fmaf(m2z[k], Z.y, d1);
            d2 = __builtin_fmaf(m2z[k], Z.z, d2);
            d3 = __builtin_fmaf(m2z[k], Z.w, d3);
            float e0 = fminf(d0, d1);
            float e1 = fminf(d2, d3);
            best[k] = fminf(best[k], fminf(e0, e1));
        }
    }

    #pragma unroll
    for (int k = 0; k < REG_N; ++k) {
        // d = p^2 + (t^2 - 2 p.t), clamped at 0 (== ref's max-then-min).
        float b = fmaxf(best[k] + p2[k], 0.0f);
        atomicMin(&dm[nbase + k * BLOCK], __float_as_uint(b));
    }
}

__global__ void chamfer_reduce(const unsigned* __restrict__ dmin, float* __restrict__ out, int N) {
    __shared__ double sacc[16];
    const int tid = threadIdx.x;
    const uint4* __restrict__ d4 = (const uint4*)dmin;
    double acc = 0.0;
    for (int i = tid; i < (2 * N) / 4; i += blockDim.x) {
        uint4 v = d4[i];
        acc += (double)__uint_as_float(v.x) + (double)__uint_as_float(v.y)
             + (double)__uint_as_float(v.z) + (double)__uint_as_float(v.w);
    }
    for (int off = 32; off; off >>= 1)
        acc += __shfl_down(acc, off, 64);
    const int wave = tid >> 6, lane = tid & 63;
    if (lane == 0) sacc[wave] = acc;
    __syncthreads();
    if (tid == 0) {
        double t = 0.0;
        int nw = blockDim.x >> 6;
        for (int w = 0; w < nw; ++w) t += sacc[w];
        out[0] = (float)(t / (double)N);   // mean(dist1) + mean(dist2), N == M
    }
}

extern "C" void kernel_launch(void* const* d_in, const int* in_sizes, int n_in,
                              void* d_out, int out_size, void* d_ws, size_t ws_size,
                              hipStream_t stream) {
    const float* predict = (const float*)d_in[0];
    const float* target  = (const float*)d_in[1];
    const int N = in_sizes[0] / 3;   // 16384 (shape [1,N,3])
    unsigned* dmin = (unsigned*)d_ws;

    init_min<<<dim3((2 * N + 255) / 256), dim3(256), 0, stream>>>(dmin, 2 * N);

    dim3 grid(N / (BLOCK * REG_N), N / CHUNK, 2);   // 16 x 32 x 2 = 1024 blocks
    chamfer_min<<<grid, dim3(BLOCK), 0, stream>>>(predict, target, dmin, N);

    chamfer_reduce<<<1, dim3(1024), 0, stream>>>(dmin, (float*)d_out, N);
}

// Round 3
// 101.634 us; speedup vs baseline: 1.2530x; 1.0128x over previous
//
#include <hip/hip_runtime.h>

#define BLOCK 256
#define REG_N 8      // owned points per thread (registers)
#define CHUNK 256    // target points staged in LDS per block (4 KB SoA incl t^2)

// dmin[0..N)  = dist1 (min over targets for each predict point), uint-encoded float
// dmin[N..2N) = dist2 (min over predicts for each target point)
// Non-negative IEEE floats compare identically as unsigned ints -> atomicMin(uint).

__global__ void init_min(unsigned* __restrict__ dmin, int n2) {
    int i = blockIdx.x * blockDim.x + threadIdx.x;
    if (i < n2) dmin[i] = 0x7F800000u;  // +inf
}

__global__ __launch_bounds__(BLOCK, 4) void chamfer_min(
    const float* __restrict__ predict, const float* __restrict__ target,
    unsigned* __restrict__ dmin, int N)
{
    const int dir = blockIdx.z;                    // 0: min over targets, 1: min over predicts
    const float* __restrict__ A = dir ? target : predict;   // points we own
    const float* __restrict__ B = dir ? predict : target;   // points we search
    unsigned* __restrict__ dm = dmin + dir * N;

    __shared__ float sx[CHUNK], sy[CHUNK], sz[CHUNK], st2[CHUNK];

    const int tid = threadIdx.x;
    const int m0  = blockIdx.y * CHUNK;

    // Stage B chunk into LDS (SoA) + per-target |t|^2. One point per thread.
    {
        int j = tid;  // BLOCK == CHUNK
        float x = B[3 * (m0 + j) + 0];
        float y = B[3 * (m0 + j) + 1];
        float z = B[3 * (m0 + j) + 2];
        sx[j] = x; sy[j] = y; sz[j] = z;
        st2[j] = __builtin_fmaf(x, x, __builtin_fmaf(y, y, z * z));
    }

    // This thread's REG_N owned points: precompute -2*p and |p|^2.
    float m2x[REG_N], m2y[REG_N], m2z[REG_N], p2[REG_N];
    const int nbase = blockIdx.x * (BLOCK * REG_N) + tid;
    #pragma unroll
    for (int k = 0; k < REG_N; ++k) {
        int n = nbase + k * BLOCK;
        float x = A[3 * n + 0], y = A[3 * n + 1], z = A[3 * n + 2];
        m2x[k] = -2.0f * x; m2y[k] = -2.0f * y; m2z[k] = -2.0f * z;
        p2[k]  = __builtin_fmaf(x, x, __builtin_fmaf(y, y, z * z));
    }

    __syncthreads();

    float best[REG_N];
    #pragma unroll
    for (int k = 0; k < REG_N; ++k) best[k] = 3.0e38f;

    const float4* __restrict__ sx4 = (const float4*)sx;
    const float4* __restrict__ sy4 = (const float4*)sy;
    const float4* __restrict__ sz4 = (const float4*)sz;
    const float4* __restrict__ st4 = (const float4*)st2;

    // Inner loop: 4 targets per iteration, shared across REG_N owned points.
    // Per k: 12 v_fma_f32 + 2 v_min3_f32 (chained fminf -> min3 combine)
    // = 3.5 VALU instr/pair. 4 ds_read_b128 amortized over 4*REG_N pairs.
    #pragma unroll 2
    for (int m = 0; m < CHUNK / 4; ++m) {
        float4 X = sx4[m], Y = sy4[m], Z = sz4[m], T = st4[m];
        #pragma unroll
        for (int k = 0; k < REG_N; ++k) {
            float d0 = __builtin_fmaf(m2x[k], X.x, T.x);
            float d1 = __builtin_fmaf(m2x[k], X.y, T.y);
            float d2 = __builtin_fmaf(m2x[k], X.z, T.z);
            float d3 = __builtin_fmaf(m2x[k], X.w, T.w);
            d0 = __builtin_fmaf(m2y[k], Y.x, d0);
            d1 = __builtin_fmaf(m2y[k], Y.y, d1);
            d2 = __builtin_fmaf(m2y[k], Y.z, d2);
            d3 = __builtin_fmaf(m2y[k], Y.w, d3);
            d0 = __builtin_fmaf(m2z[k], Z.x, d0);
            d1 = __builtin_fmaf(m2z[k], Z.y, d1);
            d2 = __builtin_fmaf(m2z[k], Z.z, d2);
            d3 = __builtin_fmaf(m2z[k], Z.w, d3);
            // chained mins -> v_min3_f32 x2: min3(d0,d1,d2), min3(.,d3,best)
            float e0 = fminf(fminf(d0, d1), d2);
            best[k] = fminf(fminf(e0, d3), best[k]);
        }
    }

    #pragma unroll
    for (int k = 0; k < REG_N; ++k) {
        // d = p^2 + (t^2 - 2 p.t), clamped at 0 (== ref's clamp).
        float b = fmaxf(best[k] + p2[k], 0.0f);
        atomicMin(&dm[nbase + k * BLOCK], __float_as_uint(b));
    }
}

__global__ void chamfer_reduce(const unsigned* __restrict__ dmin, float* __restrict__ out, int N) {
    __shared__ double sacc[16];
    const int tid = threadIdx.x;
    const uint4* __restrict__ d4 = (const uint4*)dmin;
    double acc = 0.0;
    for (int i = tid; i < (2 * N) / 4; i += blockDim.x) {
        uint4 v = d4[i];
        acc += (double)__uint_as_float(v.x) + (double)__uint_as_float(v.y)
             + (double)__uint_as_float(v.z) + (double)__uint_as_float(v.w);
    }
    for (int off = 32; off; off >>= 1)
        acc += __shfl_down(acc, off, 64);
    const int wave = tid >> 6, lane = tid & 63;
    if (lane == 0) sacc[wave] = acc;
    __syncthreads();
    if (tid == 0) {
        double t = 0.0;
        int nw = blockDim.x >> 6;
        for (int w = 0; w < nw; ++w) t += sacc[w];
        out[0] = (float)(t / (double)N);   // mean(dist1) + mean(dist2), N == M
    }
}

extern "C" void kernel_launch(void* const* d_in, const int* in_sizes, int n_in,
                              void* d_out, int out_size, void* d_ws, size_t ws_size,
                              hipStream_t stream) {
    const float* predict = (const float*)d_in[0];
    const float* target  = (const float*)d_in[1];
    const int N = in_sizes[0] / 3;   // 16384 (shape [1,N,3])
    unsigned* dmin = (unsigned*)d_ws;

    init_min<<<dim3((2 * N + 255) / 256), dim3(256), 0, stream>>>(dmin, 2 * N);

    dim3 grid(N / (BLOCK * REG_N), N / CHUNK, 2);   // 8 x 64 x 2 = 1024 blocks
    chamfer_min<<<grid, dim3(BLOCK), 0, stream>>>(predict, target, dmin, N);

    chamfer_reduce<<<1, dim3(1024), 0, stream>>>(dmin, (float*)d_out, N);
}

// Round 4
// 100.025 us; speedup vs baseline: 1.2731x; 1.0161x over previous
//
#include <hip/hip_runtime.h>

#define BLOCK 1024
#define REG_N 4      // owned points per thread (registers)
#define CHUNK 256    // target points staged in LDS per block (4 KB SoA incl t^2)

// dmin[0..N)  = dist1 (min over targets for each predict point), uint-encoded float
// dmin[N..2N) = dist2 (min over predicts for each target point)
// Non-negative IEEE floats compare identically as unsigned ints -> atomicMin(uint).

__device__ __forceinline__ float min3f(float a, float b, float c) {
    float r;
    asm("v_min3_f32 %0, %1, %2, %3" : "=v"(r) : "v"(a), "v"(b), "v"(c));
    return r;
}

__global__ void init_min(unsigned* __restrict__ dmin, int n2) {
    int i = blockIdx.x * blockDim.x + threadIdx.x;
    if (i < n2) dmin[i] = 0x7F800000u;  // +inf
}

__global__ __launch_bounds__(BLOCK, 8) void chamfer_min(
    const float* __restrict__ predict, const float* __restrict__ target,
    unsigned* __restrict__ dmin, int N)
{
    const int dir = blockIdx.z;                    // 0: min over targets, 1: min over predicts
    const float* __restrict__ A = dir ? target : predict;   // points we own
    const float* __restrict__ B = dir ? predict : target;   // points we search
    unsigned* __restrict__ dm = dmin + dir * N;

    __shared__ float sx[CHUNK], sy[CHUNK], sz[CHUNK], st2[CHUNK];

    const int tid = threadIdx.x;
    const int m0  = blockIdx.y * CHUNK;

    // Stage B chunk into LDS (SoA) + per-target |t|^2. First CHUNK threads.
    if (tid < CHUNK) {
        int j = tid;
        float x = B[3 * (m0 + j) + 0];
        float y = B[3 * (m0 + j) + 1];
        float z = B[3 * (m0 + j) + 2];
        sx[j] = x; sy[j] = y; sz[j] = z;
        st2[j] = __builtin_fmaf(x, x, __builtin_fmaf(y, y, z * z));
    }

    // This thread's REG_N owned points: precompute -2*p and |p|^2.
    float m2x[REG_N], m2y[REG_N], m2z[REG_N], p2[REG_N];
    const int nbase = blockIdx.x * (BLOCK * REG_N) + tid;
    #pragma unroll
    for (int k = 0; k < REG_N; ++k) {
        int n = nbase + k * BLOCK;
        float x = A[3 * n + 0], y = A[3 * n + 1], z = A[3 * n + 2];
        m2x[k] = -2.0f * x; m2y[k] = -2.0f * y; m2z[k] = -2.0f * z;
        p2[k]  = __builtin_fmaf(x, x, __builtin_fmaf(y, y, z * z));
    }

    __syncthreads();

    float best[REG_N];
    #pragma unroll
    for (int k = 0; k < REG_N; ++k) best[k] = 3.0e38f;

    const float4* __restrict__ sx4 = (const float4*)sx;
    const float4* __restrict__ sy4 = (const float4*)sy;
    const float4* __restrict__ sz4 = (const float4*)sz;
    const float4* __restrict__ st4 = (const float4*)st2;

    // Inner loop: 4 targets per iteration (wave-uniform broadcast LDS reads),
    // shared across REG_N owned points.
    // Per k: exactly 12 v_fma_f32 + 2 v_min3_f32 (inline asm) = 3.5 instr/pair.
    #pragma unroll 2
    for (int m = 0; m < CHUNK / 4; ++m) {
        float4 X = sx4[m], Y = sy4[m], Z = sz4[m], T = st4[m];
        #pragma unroll
        for (int k = 0; k < REG_N; ++k) {
            float d0 = __builtin_fmaf(m2x[k], X.x, T.x);
            float d1 = __builtin_fmaf(m2x[k], X.y, T.y);
            float d2 = __builtin_fmaf(m2x[k], X.z, T.z);
            float d3 = __builtin_fmaf(m2x[k], X.w, T.w);
            d0 = __builtin_fmaf(m2y[k], Y.x, d0);
            d1 = __builtin_fmaf(m2y[k], Y.y, d1);
            d2 = __builtin_fmaf(m2y[k], Y.z, d2);
            d3 = __builtin_fmaf(m2y[k], Y.w, d3);
            d0 = __builtin_fmaf(m2z[k], Z.x, d0);
            d1 = __builtin_fmaf(m2z[k], Z.y, d1);
            d2 = __builtin_fmaf(m2z[k], Z.z, d2);
            d3 = __builtin_fmaf(m2z[k], Z.w, d3);
            float e0 = min3f(d0, d1, d2);
            best[k] = min3f(e0, d3, best[k]);
        }
    }

    #pragma unroll
    for (int k = 0; k < REG_N; ++k) {
        // d = p^2 + (t^2 - 2 p.t), clamped at 0 (== ref's clamp).
        float b = fmaxf(best[k] + p2[k], 0.0f);
        atomicMin(&dm[nbase + k * BLOCK], __float_as_uint(b));
    }
}

__global__ void chamfer_reduce(const unsigned* __restrict__ dmin, float* __restrict__ out, int N) {
    __shared__ double sacc[16];
    const int tid = threadIdx.x;
    const uint4* __restrict__ d4 = (const uint4*)dmin;
    double acc = 0.0;
    for (int i = tid; i < (2 * N) / 4; i += blockDim.x) {
        uint4 v = d4[i];
        acc += (double)__uint_as_float(v.x) + (double)__uint_as_float(v.y)
             + (double)__uint_as_float(v.z) + (double)__uint_as_float(v.w);
    }
    for (int off = 32; off; off >>= 1)
        acc += __shfl_down(acc, off, 64);
    const int wave = tid >> 6, lane = tid & 63;
    if (lane == 0) sacc[wave] = acc;
    __syncthreads();
    if (tid == 0) {
        double t = 0.0;
        int nw = blockDim.x >> 6;
        for (int w = 0; w < nw; ++w) t += sacc[w];
        out[0] = (float)(t / (double)N);   // mean(dist1) + mean(dist2), N == M
    }
}

extern "C" void kernel_launch(void* const* d_in, const int* in_sizes, int n_in,
                              void* d_out, int out_size, void* d_ws, size_t ws_size,
                              hipStream_t stream) {
    const float* predict = (const float*)d_in[0];
    const float* target  = (const float*)d_in[1];
    const int N = in_sizes[0] / 3;   // 16384 (shape [1,N,3])
    unsigned* dmin = (unsigned*)d_ws;

    init_min<<<dim3((2 * N + 255) / 256), dim3(256), 0, stream>>>(dmin, 2 * N);

    dim3 grid(N / (BLOCK * REG_N), N / CHUNK, 2);   // 4 x 64 x 2 = 512 blocks, 2/CU, 32 waves/CU
    chamfer_min<<<grid, dim3(BLOCK), 0, stream>>>(predict, target, dmin, N);

    chamfer_reduce<<<1, dim3(1024), 0, stream>>>(dmin, (float*)d_out, N);
}

// Round 5
// 85.395 us; speedup vs baseline: 1.4912x; 1.1713x over previous
//
#include <hip/hip_runtime.h>

// Chamfer distance via MFMA: d_ij = |p|^2 + |t|^2 - 2 p.t packed into ONE
// v_mfma_f32_32x32x16_bf16 per 32x32 tile using K-slot packing (K=16):
//   coord c (x,y,z): A slots [ch,ch,cl,cl], B slots [qh,ql,qh,ql], q = -2t
//     -> (ch+cl)*(qh+ql) = -2 c_p * c_t  (exact products: bf16*bf16 fits fp32)
//   norms: A [n2h,n2l,1,1], B [1,1,n2h,n2l] -> |p|^2 + |t|^2
// hi/lo bf16 split gives ~16-bit effective mantissa -> |err| ~3e-5 << 6e-4 thr.
//
// Dual pass (z=0: rows=predict, z=1: rows=target), 4 col-groups, partial
// row-mins stored to 8 disjoint arrays (no atomics, no init). Final kernel
// takes min over col-groups, clamps at 0, sums in double, writes mean.

typedef short s16x8 __attribute__((ext_vector_type(8)));
typedef float f32x16 __attribute__((ext_vector_type(16)));

static __device__ __forceinline__ unsigned short f2bf(float f) {
    unsigned u = __float_as_uint(f);
    unsigned r = (u + 0x7FFFu + ((u >> 16) & 1u)) >> 16;  // RNE
    return (unsigned short)r;
}
static __device__ __forceinline__ float bf2f(unsigned short h) {
    return __uint_as_float(((unsigned)h) << 16);
}
static __device__ __forceinline__ void split2(float v, unsigned short& h, unsigned short& l) {
    h = f2bf(v);
    l = f2bf(v - bf2f(h));
}

union Pack16 { unsigned short u[16]; uint4 v[2]; };

// Build A-operand pack (own coords, own n2) and B-operand pack (-2*coords, own n2)
// for every point of both clouds. Layout: [point][16] bf16, 32 B per point.
__global__ void prep_pack(const float* __restrict__ predict, const float* __restrict__ target,
                          unsigned short* __restrict__ ApP, unsigned short* __restrict__ BpP,
                          unsigned short* __restrict__ ApT, unsigned short* __restrict__ BpT,
                          int N)
{
    int i = blockIdx.x * blockDim.x + threadIdx.x;
    if (i >= 2 * N) return;
    const float* src = (i < N) ? predict : target;
    unsigned short* Ap = (i < N) ? ApP : ApT;
    unsigned short* Bp = (i < N) ? BpP : BpT;
    int j = (i < N) ? i : i - N;

    float x = src[3*j], y = src[3*j+1], z = src[3*j+2];
    float n2 = __builtin_fmaf(x, x, __builtin_fmaf(y, y, z*z));

    unsigned short xh,xl,yh,yl,zh,zl,nh,nl,qxh,qxl,qyh,qyl,qzh,qzl;
    split2(x, xh, xl); split2(y, yh, yl); split2(z, zh, zl); split2(n2, nh, nl);
    split2(-2.0f*x, qxh, qxl); split2(-2.0f*y, qyh, qyl); split2(-2.0f*z, qzh, qzl);
    const unsigned short one = f2bf(1.0f);

    Pack16 a, b;
    a.u[0]=xh; a.u[1]=xh; a.u[2]=xl; a.u[3]=xl;
    a.u[4]=yh; a.u[5]=yh; a.u[6]=yl; a.u[7]=yl;
    a.u[8]=zh; a.u[9]=zh; a.u[10]=zl; a.u[11]=zl;
    a.u[12]=nh; a.u[13]=nl; a.u[14]=one; a.u[15]=one;

    b.u[0]=qxh; b.u[1]=qxl; b.u[2]=qxh; b.u[3]=qxl;
    b.u[4]=qyh; b.u[5]=qyl; b.u[6]=qyh; b.u[7]=qyl;
    b.u[8]=qzh; b.u[9]=qzl; b.u[10]=qzh; b.u[11]=qzl;
    b.u[12]=one; b.u[13]=one; b.u[14]=nh; b.u[15]=nl;

    uint4* ad = (uint4*)(Ap + (size_t)j * 16);
    uint4* bd = (uint4*)(Bp + (size_t)j * 16);
    ad[0] = a.v[0]; ad[1] = a.v[1];
    bd[0] = b.v[0]; bd[1] = b.v[1];
}

#define TB 64   // tiles per LDS chunk: 64 x 32 cols x 32 B = 64 KB

// Block: 256 threads (4 waves). Each wave owns 64 rows (2 strips of 32).
// Block covers rows [bx*256, +256), col-group blockIdx.y (N/4 cols), dir z.
__global__ __launch_bounds__(256, 2) void chamfer_main(
    const unsigned short* __restrict__ ApP, const unsigned short* __restrict__ BpP,
    const unsigned short* __restrict__ ApT, const unsigned short* __restrict__ BpT,
    float* __restrict__ partials, int N)
{
    const int dir = blockIdx.z;
    const unsigned short* __restrict__ Ap = dir ? ApT : ApP;
    const unsigned short* __restrict__ Bp = dir ? BpP : BpT;
    float* __restrict__ pout = partials + (size_t)(dir * 4 + blockIdx.y) * N;

    __shared__ unsigned short lB[TB * 32 * 16];   // 64 KB

    const int tid  = threadIdx.x;
    const int w    = tid >> 6;
    const int lane = tid & 63;
    const int lm   = lane & 31;     // MFMA row/col within tile
    const int lg   = lane >> 5;     // k-half (and C/D row-half)

    const int row0 = blockIdx.x * 256 + w * 64;

    // A fragments (hoisted for the whole kernel): lane needs A[row][k=lg*8..+7]
    const uint4* A4 = (const uint4*)Ap;
    s16x8 a0 = __builtin_bit_cast(s16x8, A4[(size_t)(row0      + lm) * 2 + lg]);
    s16x8 a1 = __builtin_bit_cast(s16x8, A4[(size_t)(row0 + 32 + lm) * 2 + lg]);

    float rm0[16], rm1[16];
    #pragma unroll
    for (int r = 0; r < 16; ++r) { rm0[r] = 3.0e38f; rm1[r] = 3.0e38f; }

    const f32x16 zc = {0.f,0.f,0.f,0.f,0.f,0.f,0.f,0.f,0.f,0.f,0.f,0.f,0.f,0.f,0.f,0.f};

    // This block's B slice: (N/4) cols, staged in chunks of TB tiles (2048 cols).
    const uint4* gB = (const uint4*)(Bp + (size_t)blockIdx.y * (N / 4) * 16);
    uint4* lds4 = (uint4*)lB;
    const int nchunk = (N / 4) / (TB * 32);

    for (int chunk = 0; chunk < nchunk; ++chunk) {
        __syncthreads();   // protect lB from previous iteration's readers
        const uint4* gsrc = gB + (size_t)chunk * (TB * 32 * 2);
        #pragma unroll
        for (int it = 0; it < (TB * 32 * 2) / 256; ++it)
            lds4[it * 256 + tid] = gsrc[it * 256 + tid];
        __syncthreads();

        #pragma unroll 2
        for (int t = 0; t < TB; ++t) {
            // B fragment: col=lm, k=lg*8..+7 -> 16 contiguous bytes
            uint4 bv = *(const uint4*)(lB + t * 512 + lm * 16 + lg * 8);
            s16x8 b = __builtin_bit_cast(s16x8, bv);
            f32x16 acc0 = __builtin_amdgcn_mfma_f32_32x32x16_bf16(a0, b, zc, 0, 0, 0);
            f32x16 acc1 = __builtin_amdgcn_mfma_f32_32x32x16_bf16(a1, b, zc, 0, 0, 0);
            #pragma unroll
            for (int r = 0; r < 16; ++r) {
                rm0[r] = fminf(rm0[r], acc0[r]);
                rm1[r] = fminf(rm1[r], acc1[r]);
            }
        }
    }

    // Reduce row-mins across the 32 col-lanes of each half (xor stays in-half).
    #pragma unroll
    for (int m = 1; m <= 16; m <<= 1) {
        #pragma unroll
        for (int r = 0; r < 16; ++r) {
            rm0[r] = fminf(rm0[r], __shfl_xor(rm0[r], m, 64));
            rm1[r] = fminf(rm1[r], __shfl_xor(rm1[r], m, 64));
        }
    }
    // C/D layout (m74/m101): row = (r&3) + 8*(r>>2) + 4*lg, col = lane&31.
    #pragma unroll
    for (int r = 0; r < 16; ++r) {
        int rl = (r & 3) + 8 * (r >> 2) + 4 * lg;
        if (lm == r) {
            pout[row0 +      rl] = rm0[r];
            pout[row0 + 32 + rl] = rm1[r];
        }
    }
}

__global__ void chamfer_reduce(const float* __restrict__ partials, float* __restrict__ out, int N) {
    __shared__ double sacc[16];
    const int tid = threadIdx.x;
    double acc = 0.0;
    for (int i = tid; i < N; i += blockDim.x) {
        float m0 = fminf(fminf(partials[i],         partials[N + i]),
                         fminf(partials[2*N + i],   partials[3*N + i]));
        float m1 = fminf(fminf(partials[4*N + i],   partials[5*N + i]),
                         fminf(partials[6*N + i],   partials[7*N + i]));
        acc += (double)fmaxf(m0, 0.0f) + (double)fmaxf(m1, 0.0f);
    }
    for (int off = 32; off; off >>= 1)
        acc += __shfl_down(acc, off, 64);
    const int wave = tid >> 6, lane = tid & 63;
    if (lane == 0) sacc[wave] = acc;
    __syncthreads();
    if (tid == 0) {
        double t = 0.0;
        int nw = blockDim.x >> 6;
        for (int wv = 0; wv < nw; ++wv) t += sacc[wv];
        out[0] = (float)(t / (double)N);   // mean(dist1) + mean(dist2), N == M
    }
}

extern "C" void kernel_launch(void* const* d_in, const int* in_sizes, int n_in,
                              void* d_out, int out_size, void* d_ws, size_t ws_size,
                              hipStream_t stream) {
    const float* predict = (const float*)d_in[0];
    const float* target  = (const float*)d_in[1];
    const int N = in_sizes[0] / 3;   // 16384

    unsigned short* ws16 = (unsigned short*)d_ws;
    unsigned short* ApP = ws16;
    unsigned short* BpP = ws16 + (size_t)1 * N * 16;
    unsigned short* ApT = ws16 + (size_t)2 * N * 16;
    unsigned short* BpT = ws16 + (size_t)3 * N * 16;
    float* partials = (float*)(ws16 + (size_t)4 * N * 16);   // 8 * N floats

    prep_pack<<<dim3((2 * N + 255) / 256), dim3(256), 0, stream>>>(
        predict, target, ApP, BpP, ApT, BpT, N);

    dim3 grid(N / 256, 4, 2);   // 64 x 4 x 2 = 512 blocks, 2/CU (LDS-capped)
    chamfer_main<<<grid, dim3(256), 0, stream>>>(ApP, BpP, ApT, BpT, partials, N);

    chamfer_reduce<<<1, dim3(1024), 0, stream>>>(partials, (float*)d_out, N);
}